// Round 2
// baseline (181.638 us; speedup 1.0000x reference)
//
#include <hip/hip_runtime.h>
#include <hip/hip_bf16.h>

// IGD metric kernel for MI355X (gfx950).
// d2(i,j) = pfsq[i] + xsq[j] + dot(Abf[i], Bbf[j])  where Abf = bf16(-2*pf), Bbf = bf16(x),
// pfsq/xsq computed from the *rounded* values so d2 is an exact squared distance of rounded vectors.
// Main kernel: per-wave persistent A fragments (64 rows), stream B in 32-col chunks via
// v_mfma_f32_32x32x16_bf16, running min of (acc + xsq) per (lane,reg), no LDS / no barriers.
// R2: NSPLIT 8->16, grid 1024 = exactly 4 blocks/CU, __launch_bounds__(256,4) -> 16 waves/CU
// (was 2 blocks/CU / 20% occupancy -> latency-bound, MfmaUtil 17.5%). Packs fused into one launch.

typedef __bf16 bf16x8 __attribute__((ext_vector_type(8)));
typedef float f32x16 __attribute__((ext_vector_type(16)));

#define DIM 64
#define NSPLIT 16
#define NCHUNK 1024   // columns per block
#define MTILE 256     // rows per block (4 waves x 64 rows)

// ---------------- pack: fp32 [rows][64] -> bf16 [rows][64] (+ per-row sum of squares) -------------
// 4 lanes per row, 16 elements each -> coalesced 16B loads/stores. Fused: rows < N are x
// (scale 1 -> Bb/xsq), rows >= N are pf (scale -2 -> Ab, sq*0.25 = pf^2 -> pfsq).
__global__ void pack_kernel(const float* __restrict__ x, const float* __restrict__ pf,
                            __bf16* __restrict__ Bb, __bf16* __restrict__ Ab,
                            float* __restrict__ xsq, float* __restrict__ pfsq, int N, int total) {
    int gid = blockIdx.x * blockDim.x + threadIdx.x;
    int row = gid >> 2, q = gid & 3;
    if (row >= total) return;
    bool isX = row < N;
    const float* s = (isX ? x + (size_t)row * DIM : pf + (size_t)(row - N) * DIM) + q * 16;
    float scale = isX ? 1.f : -2.f;
    float sqScale = isX ? 1.f : 0.25f;
    __bf16* dst = isX ? Bb + (size_t)row * DIM : Ab + (size_t)(row - N) * DIM;
    float* sq = isX ? xsq + row : pfsq + (row - N);

    float partial = 0.f;
    bf16x8 outv[2];
#pragma unroll
    for (int h = 0; h < 2; ++h) {
        float4 v0 = *(const float4*)(s + h * 8);
        float4 v1 = *(const float4*)(s + h * 8 + 4);
        float f[8] = {v0.x, v0.y, v0.z, v0.w, v1.x, v1.y, v1.z, v1.w};
#pragma unroll
        for (int i = 0; i < 8; ++i) {
            __bf16 b = (__bf16)(f[i] * scale);
            outv[h][i] = b;
            float bb = (float)b;
            partial += bb * bb;
        }
    }
    *(bf16x8*)(dst + q * 16)     = outv[0];
    *(bf16x8*)(dst + q * 16 + 8) = outv[1];
    partial += __shfl_xor(partial, 1);
    partial += __shfl_xor(partial, 2);
    if (q == 0) *sq = partial * sqScale;
}

// ---------------- main: fused GEMM + row-min ----------------
// A: bf16(-2*pf) [M][64], B: bf16(x) [N][64], xsq: [N]
// partial[row][nsplit] = min over this split's columns of (xsq[col] - 2*pf[row].x[col])
__global__ __launch_bounds__(256, 4)
void igd_main(const __bf16* __restrict__ A, const __bf16* __restrict__ B,
              const float* __restrict__ xsq, float* __restrict__ partial) {
    const int mTile  = blockIdx.x;
    const int nsplit = blockIdx.y;
    const int lane = threadIdx.x & 63;
    const int wave = threadIdx.x >> 6;
    const int half = lane >> 5;     // 0/1
    const int l31  = lane & 31;
    const int rowBase = mTile * MTILE + wave * 64;

    // Persistent A fragments: 2 row-groups x 4 K-frags.
    // A-operand layout (32x32x16): lane holds A[row = lane&31][k = (lane>>5)*8 + j], j=0..7
    bf16x8 a[2][4];
#pragma unroll
    for (int g = 0; g < 2; ++g) {
        const __bf16* ap = A + (size_t)(rowBase + 32 * g + l31) * DIM + half * 8;
#pragma unroll
        for (int kf = 0; kf < 4; ++kf)
            a[g][kf] = *(const bf16x8*)(ap + kf * 16);
    }

    f32x16 zero, m0, m1;
#pragma unroll
    for (int r = 0; r < 16; ++r) { zero[r] = 0.f; m0[r] = 1e30f; m1[r] = 1e30f; }

    const int colBase0 = nsplit * NCHUNK;
    // B-operand layout: lane holds B[k = (lane>>5)*8 + i][col = lane&31]
    //   = x_bf16[col*64 + (lane>>5)*8 + i]  -> one 16B load per K-frag
    const __bf16* bbase = B + (size_t)(colBase0 + l31) * DIM + half * 8;
    const int CHUNKS = NCHUNK / 32;

    // prefetch chunk 0
    bf16x8 bcur[4];
#pragma unroll
    for (int kf = 0; kf < 4; ++kf) bcur[kf] = *(const bf16x8*)(bbase + kf * 16);
    float xq_cur = xsq[colBase0 + l31];

#pragma unroll 2
    for (int c = 0; c < CHUNKS; ++c) {
        // prefetch next chunk (wrap to 0 on last iter: harmless in-bounds load)
        int cn = (c + 1 < CHUNKS) ? c + 1 : 0;
        const __bf16* nb = bbase + (size_t)cn * 32 * DIM;
        bf16x8 bnext[4];
#pragma unroll
        for (int kf = 0; kf < 4; ++kf) bnext[kf] = *(const bf16x8*)(nb + kf * 16);
        float xq_next = xsq[colBase0 + cn * 32 + l31];

        f32x16 acc0 = __builtin_amdgcn_mfma_f32_32x32x16_bf16(a[0][0], bcur[0], zero, 0, 0, 0);
        f32x16 acc1 = __builtin_amdgcn_mfma_f32_32x32x16_bf16(a[1][0], bcur[0], zero, 0, 0, 0);
#pragma unroll
        for (int kf = 1; kf < 4; ++kf) {
            acc0 = __builtin_amdgcn_mfma_f32_32x32x16_bf16(a[0][kf], bcur[kf], acc0, 0, 0, 0);
            acc1 = __builtin_amdgcn_mfma_f32_32x32x16_bf16(a[1][kf], bcur[kf], acc1, 0, 0, 0);
        }
#pragma unroll
        for (int r = 0; r < 16; ++r) {
            m0[r] = fminf(m0[r], acc0[r] + xq_cur);
            m1[r] = fminf(m1[r], acc1[r] + xq_cur);
        }
#pragma unroll
        for (int kf = 0; kf < 4; ++kf) bcur[kf] = bnext[kf];
        xq_cur = xq_next;
    }

    // cross-lane min over the 32 lanes sharing a row (low 5 lane bits)
#pragma unroll
    for (int mask = 1; mask <= 16; mask <<= 1) {
#pragma unroll
        for (int r = 0; r < 16; ++r) {
            m0[r] = fminf(m0[r], __shfl_xor(m0[r], mask));
            m1[r] = fminf(m1[r], __shfl_xor(m1[r], mask));
        }
    }
    if (l31 == 0) {
        // C/D layout: row = (r&3) + 8*(r>>2) + 4*(lane>>5)
#pragma unroll
        for (int r = 0; r < 16; ++r) {
            int row0 = rowBase + (r & 3) + 8 * (r >> 2) + 4 * half;
            partial[(size_t)row0 * NSPLIT + nsplit] = m0[r];
            partial[(size_t)(row0 + 32) * NSPLIT + nsplit] = m1[r];
        }
    }
}

// ---------------- reduce: min over splits, sqrt, mean ----------------
__global__ void reduce_kernel(const float* __restrict__ partial, const float* __restrict__ pfsq,
                              float* __restrict__ out, int M, float invM) {
    int row = blockIdx.x * blockDim.x + threadIdx.x;
    float v = 0.f;
    if (row < M) {
        const float* p = partial + (size_t)row * NSPLIT;
        float mn = 3.4e38f;
#pragma unroll
        for (int s = 0; s < NSPLIT; ++s) mn = fminf(mn, p[s]);
        float d2 = mn + pfsq[row];
        v = sqrtf(fmaxf(d2, 0.f)) * invM;
    }
#pragma unroll
    for (int m = 1; m < 64; m <<= 1) v += __shfl_xor(v, m);
    __shared__ float wsum[4];
    int lane = threadIdx.x & 63, w = threadIdx.x >> 6;
    if (lane == 0) wsum[w] = v;
    __syncthreads();
    if (threadIdx.x == 0) atomicAdd(out, wsum[0] + wsum[1] + wsum[2] + wsum[3]);
}

extern "C" void kernel_launch(void* const* d_in, const int* in_sizes, int n_in,
                              void* d_out, int out_size, void* d_ws, size_t ws_size,
                              hipStream_t stream) {
    const float* x  = (const float*)d_in[0];   // [N, 64]
    const float* pf = (const float*)d_in[1];   // [M, 64]
    const int N = in_sizes[0] / DIM;
    const int M = in_sizes[1] / DIM;

    char* ws = (char*)d_ws;
    __bf16* Bb   = (__bf16*)ws;                                   // N*64*2 bytes
    __bf16* Ab   = (__bf16*)(ws + (size_t)N * DIM * 2);           // M*64*2 bytes
    float*  xsq  = (float*)(ws + (size_t)(N + M) * DIM * 2);      // N floats
    float*  pfsq = xsq + N;                                       // M floats
    float*  part = pfsq + M;                                      // M*NSPLIT floats

    hipMemsetAsync(d_out, 0, sizeof(float), stream);
    int totalRows = N + M;
    pack_kernel<<<dim3((totalRows * 4 + 255) / 256), 256, 0, stream>>>(x, pf, Bb, Ab, xsq, pfsq, N, totalRows);
    igd_main<<<dim3(M / MTILE, NSPLIT), 256, 0, stream>>>(Ab, Bb, xsq, part);
    reduce_kernel<<<dim3((M + 255) / 256), 256, 0, stream>>>(part, pfsq, (float*)d_out, M, 1.f / (float)M);
}

// Round 3
// 100.640 us; speedup vs baseline: 1.8048x; 1.8048x over previous
//
#include <hip/hip_runtime.h>
#include <hip/hip_bf16.h>

// IGD metric kernel for MI355X (gfx950).
// d2(i,j) = pfsq[i] + xsq[j] + dot(Abf[i], Bbf[j]), Abf = bf16(-2*pf), Bbf = bf16(x);
// norms from rounded values -> exact sq-distance of rounded vectors (absmax ~0 on the mean).
// R3: B packed to MFMA-fragment-linear layout (dense 1KB wave loads; R1's strided loads made
// the L1/TA path the bottleneck: 32 lines per load instr), 3 blocks/CU via launch_bounds(256,3)
// with 12 ragged splits (R2's (256,4) forced 64 VGPRs -> 100MB spill traffic), explicit
// ping-pong prefetch regs, d_out zeroing folded into pack.

typedef __bf16 bf16x8 __attribute__((ext_vector_type(8)));
typedef float f32x16 __attribute__((ext_vector_type(16)));

#define DIM 64
#define NSPLIT 12
#define MTILE 256     // rows per block (4 waves x 64 rows)

// ---------------- pack ----------------
// x -> Bp in fragment order: unit u (32 cols), kf (16-k block), lane = half*32 + (col&31),
//   slot 8 elems: Bp[((u*4+kf)*64 + lane)*8 + j] = bf16(x[col][kf*16 + half*8 + j])
// pf -> Ab row-major bf16(-2*pf); xsq/pfsq = sum of squares of rounded values.
__global__ void pack_kernel(const float* __restrict__ x, const float* __restrict__ pf,
                            __bf16* __restrict__ Bp, __bf16* __restrict__ Ab,
                            float* __restrict__ xsq, float* __restrict__ pfsq,
                            float* __restrict__ out, int N, int M) {
    int gid = blockIdx.x * blockDim.x + threadIdx.x;
    if (gid == 0) out[0] = 0.f;
    if (gid < N * 4) {
        int col = gid >> 2, kf = gid & 3;
        const float* s = x + (size_t)col * DIM + kf * 16;
        float partial = 0.f;
        bf16x8 outv[2];
#pragma unroll
        for (int h = 0; h < 2; ++h) {
            float4 v0 = *(const float4*)(s + h * 8);
            float4 v1 = *(const float4*)(s + h * 8 + 4);
            float f[8] = {v0.x, v0.y, v0.z, v0.w, v1.x, v1.y, v1.z, v1.w};
#pragma unroll
            for (int i = 0; i < 8; ++i) {
                __bf16 b = (__bf16)f[i];
                outv[h][i] = b;
                float bb = (float)b;
                partial += bb * bb;
            }
        }
        int u = col >> 5, c31 = col & 31;
        *(bf16x8*)(Bp + ((size_t)(u * 4 + kf) * 64 + c31) * 8)      = outv[0];
        *(bf16x8*)(Bp + ((size_t)(u * 4 + kf) * 64 + 32 + c31) * 8) = outv[1];
        partial += __shfl_xor(partial, 1);
        partial += __shfl_xor(partial, 2);
        if (kf == 0) xsq[col] = partial;
    } else {
        int g = gid - N * 4;
        int row = g >> 2, q = g & 3;
        if (row >= M) return;
        const float* s = pf + (size_t)row * DIM + q * 16;
        float partial = 0.f;
        bf16x8 outv[2];
#pragma unroll
        for (int h = 0; h < 2; ++h) {
            float4 v0 = *(const float4*)(s + h * 8);
            float4 v1 = *(const float4*)(s + h * 8 + 4);
            float f[8] = {v0.x, v0.y, v0.z, v0.w, v1.x, v1.y, v1.z, v1.w};
#pragma unroll
            for (int i = 0; i < 8; ++i) {
                __bf16 b = (__bf16)(f[i] * -2.f);
                outv[h][i] = b;
                float bb = (float)b;
                partial += bb * bb;
            }
        }
        *(bf16x8*)(Ab + (size_t)row * DIM + q * 16)     = outv[0];
        *(bf16x8*)(Ab + (size_t)row * DIM + q * 16 + 8) = outv[1];
        partial += __shfl_xor(partial, 1);
        partial += __shfl_xor(partial, 2);
        if (q == 0) pfsq[row] = partial * 0.25f;
    }
}

// ---------------- main: fused GEMM + row-min ----------------
__global__ __launch_bounds__(256, 3)
void igd_main(const __bf16* __restrict__ A, const __bf16* __restrict__ Bp,
              const float* __restrict__ xsq, float* __restrict__ partial, int N) {
    const int mTile  = blockIdx.x;
    const int nsplit = blockIdx.y;
    const int lane = threadIdx.x & 63;
    const int wave = threadIdx.x >> 6;
    const int half = lane >> 5;
    const int l31  = lane & 31;
    const int rowBase = mTile * MTILE + wave * 64;

    // ragged split: units of 32 cols
    const int utotal = N / 32;                       // 512
    const int ubase  = utotal / NSPLIT;              // 42
    const int urem   = utotal % NSPLIT;              // 8
    const int ustart = nsplit * ubase + (nsplit < urem ? nsplit : urem);
    const int ucount = ubase + (nsplit < urem ? 1 : 0);

    // Persistent A fragments: lane holds A[row=lane&31][k=(lane>>5)*8 + j]
    bf16x8 a[2][4];
#pragma unroll
    for (int g = 0; g < 2; ++g) {
        const __bf16* ap = A + (size_t)(rowBase + 32 * g + l31) * DIM + half * 8;
#pragma unroll
        for (int kf = 0; kf < 4; ++kf)
            a[g][kf] = *(const bf16x8*)(ap + kf * 16);
    }

    f32x16 zero, m0, m1;
#pragma unroll
    for (int r = 0; r < 16; ++r) { zero[r] = 0.f; m0[r] = 1e30f; m1[r] = 1e30f; }

    // packed B: unit stride 2048 elems; within unit: kf*512 + lane*8
    const __bf16* bbase = Bp + (size_t)ustart * 2048 + (size_t)lane * 8;
    const float*  xbase = xsq + ustart * 32 + l31;

    bf16x8 bA[4], bB[4];
    float xqA, xqB;

#define LOADU(breg, xq, u)                                                     \
    {                                                                          \
        const __bf16* p = bbase + (size_t)(u) * 2048;                          \
        breg[0] = *(const bf16x8*)(p);                                         \
        breg[1] = *(const bf16x8*)(p + 512);                                   \
        breg[2] = *(const bf16x8*)(p + 1024);                                  \
        breg[3] = *(const bf16x8*)(p + 1536);                                  \
        xq = xbase[(u) * 32];                                                  \
    }

#define COMPUTE(breg, xq)                                                      \
    {                                                                          \
        f32x16 acc0 = __builtin_amdgcn_mfma_f32_32x32x16_bf16(a[0][0], breg[0], zero, 0, 0, 0); \
        f32x16 acc1 = __builtin_amdgcn_mfma_f32_32x32x16_bf16(a[1][0], breg[0], zero, 0, 0, 0); \
        _Pragma("unroll")                                                      \
        for (int kf = 1; kf < 4; ++kf) {                                       \
            acc0 = __builtin_amdgcn_mfma_f32_32x32x16_bf16(a[0][kf], breg[kf], acc0, 0, 0, 0); \
            acc1 = __builtin_amdgcn_mfma_f32_32x32x16_bf16(a[1][kf], breg[kf], acc1, 0, 0, 0); \
        }                                                                      \
        _Pragma("unroll")                                                      \
        for (int r = 0; r < 16; ++r) {                                         \
            m0[r] = fminf(m0[r], acc0[r] + xq);                                \
            m1[r] = fminf(m1[r], acc1[r] + xq);                                \
        }                                                                      \
    }

    LOADU(bA, xqA, 0);
    int u = 0;
    for (; u + 2 < ucount; u += 2) {
        LOADU(bB, xqB, u + 1);
        COMPUTE(bA, xqA);
        LOADU(bA, xqA, u + 2);
        COMPUTE(bB, xqB);
    }
    if (u + 1 < ucount) {
        LOADU(bB, xqB, u + 1);
        COMPUTE(bA, xqA);
        COMPUTE(bB, xqB);
    } else {
        COMPUTE(bA, xqA);
    }
#undef LOADU
#undef COMPUTE

    // cross-lane min over the 32 lanes sharing a row
#pragma unroll
    for (int mask = 1; mask <= 16; mask <<= 1) {
#pragma unroll
        for (int r = 0; r < 16; ++r) {
            m0[r] = fminf(m0[r], __shfl_xor(m0[r], mask));
            m1[r] = fminf(m1[r], __shfl_xor(m1[r], mask));
        }
    }
    if (l31 == 0) {
        // C/D layout: row = (r&3) + 8*(r>>2) + 4*half
#pragma unroll
        for (int r = 0; r < 16; ++r) {
            int row0 = rowBase + (r & 3) + 8 * (r >> 2) + 4 * half;
            partial[(size_t)row0 * NSPLIT + nsplit] = m0[r];
            partial[(size_t)(row0 + 32) * NSPLIT + nsplit] = m1[r];
        }
    }
}

// ---------------- reduce: min over splits, sqrt, mean ----------------
__global__ void reduce_kernel(const float* __restrict__ partial, const float* __restrict__ pfsq,
                              float* __restrict__ out, int M, float invM) {
    int row = blockIdx.x * blockDim.x + threadIdx.x;
    float v = 0.f;
    if (row < M) {
        const float* p = partial + (size_t)row * NSPLIT;
        float mn = 3.4e38f;
#pragma unroll
        for (int s = 0; s < NSPLIT; ++s) mn = fminf(mn, p[s]);
        float d2 = mn + pfsq[row];
        v = sqrtf(fmaxf(d2, 0.f)) * invM;
    }
#pragma unroll
    for (int m = 1; m < 64; m <<= 1) v += __shfl_xor(v, m);
    __shared__ float wsum[4];
    int lane = threadIdx.x & 63, w = threadIdx.x >> 6;
    if (lane == 0) wsum[w] = v;
    __syncthreads();
    if (threadIdx.x == 0) atomicAdd(out, wsum[0] + wsum[1] + wsum[2] + wsum[3]);
}

extern "C" void kernel_launch(void* const* d_in, const int* in_sizes, int n_in,
                              void* d_out, int out_size, void* d_ws, size_t ws_size,
                              hipStream_t stream) {
    const float* x  = (const float*)d_in[0];   // [N, 64]
    const float* pf = (const float*)d_in[1];   // [M, 64]
    const int N = in_sizes[0] / DIM;
    const int M = in_sizes[1] / DIM;

    char* ws = (char*)d_ws;
    __bf16* Bp   = (__bf16*)ws;                                   // N*64*2 bytes (packed)
    __bf16* Ab   = (__bf16*)(ws + (size_t)N * DIM * 2);           // M*64*2 bytes
    float*  xsq  = (float*)(ws + (size_t)(N + M) * DIM * 2);      // N floats
    float*  pfsq = xsq + N;                                       // M floats
    float*  part = pfsq + M;                                      // M*NSPLIT floats

    int packThreads = (N + M) * 4;
    pack_kernel<<<dim3((packThreads + 255) / 256), 256, 0, stream>>>(
        x, pf, Bp, Ab, xsq, pfsq, (float*)d_out, N, M);
    igd_main<<<dim3(M / MTILE, NSPLIT), 256, 0, stream>>>(Ab, Bp, xsq, part, N);
    reduce_kernel<<<dim3((M + 255) / 256), 256, 0, stream>>>(part, pfsq, (float*)d_out, M, 1.f / (float)M);
}